// Round 11
// baseline (346.800 us; speedup 1.0000x reference)
//
#include <hip/hip_runtime.h>
#include <math.h>

// SampleScoreModel fused flash kernel — fp32 in/out. R10: 213us (flash 145),
// LDS-pipe-bound: 8 waves x ~61 b128/iter x ~12cyc ~= the whole iter budget;
// 4x wave redundancy on B-frag reads (16x16 MFMA ties waves to 16 rows).
// R11: 32x32x16 MFMA, BM=128 (wave=32 rows) -> 2x work per B-read; 1 block/CU
// (VGPR ~370, 1 wave/SIMD) + double-buffered LDS (106KB) + global_load_lds
// dwordx4 DMA staging of pre-swizzled bf16 planes (zero staging VALU).
// Planes (prep kernels): gkhi/gklo = samples bf16 hi/lo, 16B-chunk XOR-swizzled
// by row; gvt = tile-blocked transposed V, chunk-swizzled; gxhi/gxlo = x hi/lo;
// gs2 = 0.5*||s||^2. pO stored bf16 (ws fit; +<0.5 err).

typedef float  f32x16 __attribute__((ext_vector_type(16)));
typedef short  s16x8  __attribute__((ext_vector_type(8)));
typedef unsigned short u16;
typedef unsigned int   u32;

#define LOG2E   1.44269504088896f
#define L2_10K  13.2877123795494f   /* log2(10000) */
#define L2_001 -6.64385618977472f   /* log2(0.01)  */
#define SMIN2   1e-8f               /* SIGMA_MIN^2 */
#define DDIM    256

#if defined(__has_builtin)
#if __has_builtin(__builtin_amdgcn_exp2f)
#define EXP2(x) __builtin_amdgcn_exp2f(x)
#endif
#endif
#ifndef EXP2
#define EXP2(x) exp2f(x)
#endif

__device__ __forceinline__ u16 bf16_rne(float f) {
  u32 u = __builtin_bit_cast(u32, f);
  u = (u + 0x7FFFu + ((u >> 16) & 1u)) >> 16;
  return (u16)u;
}
__device__ __forceinline__ float bf16_to_f(u16 h) {
  u32 u = ((u32)h) << 16;
  return __builtin_bit_cast(float, u);
}
__device__ __forceinline__ float f16_to_f(u16 h) {
  int s = (h >> 15) & 1, e = (h >> 10) & 31, m = h & 1023;
  float v;
  if (e == 0)       v = ldexpf((float)m, -24);
  else if (e == 31) v = 3.0e38f;
  else              v = ldexpf((float)(1024 + m), e - 25);
  return s ? -v : v;
}
__device__ __forceinline__ int classify_t_dtype(const void* tp) {
  const u16* u16p = (const u16*)tp;
  const u32* u32p = (const u32*)tp;
  int c16 = 0, c32 = 0;
  for (int i = 0; i < 128; ++i) {
    u16 u = u16p[i];
    int e = (u >> 7) & 0xFF;
    if (!(u & 0x8000) && e >= 113 && e <= 126) c16++;
  }
  for (int i = 0; i < 64; ++i) {
    u32 w = u32p[i];
    int e = (int)((w >> 23) & 0xFF);
    if (!(w & 0x80000000u) && e >= 113 && e <= 126) c32++;
  }
  if (c32 >= 51) return (c16 >= 102) ? 0 : 1;   // 0=bf16, 1=fp32
  return 2;                                      // 2=fp16
}
__device__ __forceinline__ float load_t(const void* tp, int i, int mode) {
  float v;
  if (mode == 0)      v = bf16_to_f(((const u16*)tp)[i]);
  else if (mode == 1) v = ((const float*)tp)[i];
  else                v = f16_to_f(((const u16*)tp)[i]);
  return fminf(fmaxf(v, 0.f), 1.f);
}

// async 16B global->LDS DMA: lds ptr must be wave-uniform; HW adds lane*16.
__device__ __forceinline__ void dma16(const void* g, void* l) {
  __builtin_amdgcn_global_load_lds((const __attribute__((address_space(1))) u32*)g,
                                   (__attribute__((address_space(3))) u32*)l, 16, 0, 0);
}

// ---------------- precompute kernels ----------------

// gkhi/gklo: samples bf16 hi/lo, row-major, 16B chunks stored at c^(row&31).
// gs2[row] = 0.5*||s_row||^2 (exact fp32).
__global__ __launch_bounds__(256)
void prep_rows(const float* __restrict__ smp, u16* __restrict__ gkhi,
               u16* __restrict__ gklo, float* __restrict__ gs2, int N)
{
  int row  = blockIdx.x * 4 + (threadIdx.x >> 6);
  int lane = threadIdx.x & 63;
  float4 v4 = *(const float4*)(smp + (size_t)row * DDIM + lane * 4);
  float v[4] = {v4.x, v4.y, v4.z, v4.w};
  u16 hh[4], ll[4];
  float s2 = 0.f;
#pragma unroll
  for (int e = 0; e < 4; ++e) {
    hh[e] = bf16_rne(v[e]);
    ll[e] = bf16_rne(v[e] - bf16_to_f(hh[e]));
    s2 = fmaf(v[e], v[e], s2);
  }
  int c  = lane >> 1;                       // 16B chunk 0..31 (2 lanes per chunk)
  int cp = c ^ (row & 31);
  size_t off = (size_t)row * DDIM + cp * 8 + (lane & 1) * 4;
  *(ushort4*)(gkhi + off) = make_ushort4(hh[0], hh[1], hh[2], hh[3]);
  *(ushort4*)(gklo + off) = make_ushort4(ll[0], ll[1], ll[2], ll[3]);
#pragma unroll
  for (int msk = 1; msk <= 32; msk <<= 1) s2 += __shfl_xor(s2, msk);
  if (lane == 0) gs2[row] = 0.5f * s2;
}

// gxhi/gxlo: x bf16 hi/lo, plain row-major.
__global__ __launch_bounds__(256)
void prep_x(const float* __restrict__ x, u16* __restrict__ gxhi,
            u16* __restrict__ gxlo, int B)
{
  int row  = blockIdx.x * 4 + (threadIdx.x >> 6);
  int lane = threadIdx.x & 63;
  float4 v4 = *(const float4*)(x + (size_t)row * DDIM + lane * 4);
  float v[4] = {v4.x, v4.y, v4.z, v4.w};
  u16 hh[4], ll[4];
#pragma unroll
  for (int e = 0; e < 4; ++e) {
    hh[e] = bf16_rne(v[e]);
    ll[e] = bf16_rne(v[e] - bf16_to_f(hh[e]));
  }
  size_t off = (size_t)row * DDIM + lane * 4;
  *(ushort4*)(gxhi + off) = make_ushort4(hh[0], hh[1], hh[2], hh[3]);
  *(ushort4*)(gxlo + off) = make_ushort4(ll[0], ll[1], ll[2], ll[3]);
}

// gvt: tile-blocked transposed V (bf16 hi): tile tb, row d (0..255), 32 n-vals;
// 16B chunks (8 n each) stored at j^(d&3).
__global__ __launch_bounds__(256)
void prep_t(const float* __restrict__ smp, u16* __restrict__ gvt, int N)
{
  int d  = threadIdx.x;
  int n0 = blockIdx.x * 32;
  u16 buf[32];
#pragma unroll
  for (int i = 0; i < 32; ++i)
    buf[i] = bf16_rne(smp[(size_t)(n0 + i) * DDIM + d]);   // coalesced across threads
  u16* dst = gvt + ((size_t)blockIdx.x * 256 + d) * 32;
#pragma unroll
  for (int j = 0; j < 4; ++j)
    *(s16x8*)(dst + 8 * (j ^ (d & 3))) = *(s16x8*)&buf[j * 8];
}

// ---------------- flash kernel (32x32x16 MFMA, BM=128, dbuf DMA) ----------------

#define PSTR 40   /* P row stride (u16): 80B, 16B-aligned */

struct __align__(16) Smem {
  u16 kh[2][8192];      // 2 x 16 KB  K tile bf16-hi (swizzled chunks)
  u16 kl[2][8192];      // 2 x 16 KB  K tile bf16-lo
  u16 vt[2][8192];      // 2 x 16 KB  V^T tile (swizzled chunks)
  u16 p[4][32 * PSTR];  // 10 KB      per-wave P round-trip
};  // 108,544 B -> 1 block/CU (intended; VGPR ~370 -> 1 wave/SIMD)

__global__ __launch_bounds__(256)
void flash_kernel(const void* __restrict__ t,
                  const u16* __restrict__ gkhi, const u16* __restrict__ gklo,
                  const u16* __restrict__ gvt,  const float* __restrict__ gs2,
                  const u16* __restrict__ gxhi, const u16* __restrict__ gxlo,
                  u16* __restrict__ pO, float* __restrict__ pm,
                  float* __restrict__ pl, int B, int N)
{
  __shared__ Smem sm;
  const int tid  = threadIdx.x;
  const int wave = tid >> 6, lane = tid & 63;
  const int h    = lane >> 5, col = lane & 31;     // half, column (n or d)
  const int m0w  = blockIdx.x * 128 + wave * 32;   // wave owns 32 m-rows
  const int nsplit = gridDim.y, split = blockIdx.y;
  const int n_per = N / nsplit;
  const int n0b  = split * n_per;
  const int iters = n_per >> 5;                    // BN = 32
  const int tmode = classify_t_dtype(t);

  // per-row C-layout: row(r) = (r&3) + 8*(r>>2) + 4*h
  float invd[16];
#pragma unroll
  for (int r = 0; r < 16; ++r) {
    int gm = m0w + (r & 3) + 8 * (r >> 2) + 4 * h;
    float tv = load_t(t, gm, tmode);
    float ts = EXP2(fmaf(tv, L2_10K, L2_001));
    invd[r] = LOG2E / (ts * ts + SMIN2);
  }

  // Q fragments: A-layout row = lane&31 (wave-local), k = kc*16 + 8*h + j
  s16x8 qh[16], ql[16];
  {
    const u16* xh = gxhi + (size_t)(m0w + col) * DDIM + 8 * h;
    const u16* xl = gxlo + (size_t)(m0w + col) * DDIM + 8 * h;
#pragma unroll
    for (int kc = 0; kc < 16; ++kc) {
      qh[kc] = *(const s16x8*)(xh + kc * 16);
      ql[kc] = *(const s16x8*)(xl + kc * 16);
    }
  }

  f32x16 O[8];
#pragma unroll
  for (int dt = 0; dt < 8; ++dt)
#pragma unroll
    for (int r = 0; r < 16; ++r) O[dt][r] = 0.f;
  float mrun[16], lrun[16];
#pragma unroll
  for (int r = 0; r < 16; ++r) { mrun[r] = -1e30f; lrun[r] = 0.f; }

  // ---- DMA staging: 12 x 16B per thread per tile; lds base wave-uniform ----
  const int l8 = lane * 8;                         // u16 offset of lane's 16B
#define STAGE(buf, n0)                                                        \
  {                                                                           \
    const size_t kb = (size_t)(n0) * DDIM;                                    \
    const size_t vb = (size_t)((n0) >> 5) * 8192;                             \
    _Pragma("unroll")                                                         \
    for (int c = 0; c < 4; ++c) {                                             \
      int bo = (wave * 4 + c) * 512;                                          \
      dma16(gkhi + kb + bo + l8, &sm.kh[buf][bo]);                            \
      dma16(gklo + kb + bo + l8, &sm.kl[buf][bo]);                            \
      dma16(gvt  + vb + bo + l8, &sm.vt[buf][bo]);                            \
    }                                                                         \
  }

  STAGE(0, n0b)
  float s2pre = gs2[n0b + col];                    // tile-0 s2 prefetch

  int n0 = n0b;
  for (int it = 0; it < iters; ++it) {
    __syncthreads();   // DMA for buf cb drained; all waves done with buf cb^1
    const int cb = it & 1;
    float nege = -s2pre;
    if (it + 1 < iters) {
      STAGE(cb ^ 1, n0 + 32)
      s2pre = gs2[n0 + 32 + col];
    }

    // ---- QK^T: 3-pass split bf16, acc init = -0.5*||s_n||^2 (n = col) ----
    f32x16 acc;
#pragma unroll
    for (int r = 0; r < 16; ++r) acc[r] = nege;
    {
      const u16* KH = sm.kh[cb] + col * DDIM;      // row = n = col
      const u16* KL = sm.kl[cb] + col * DDIM;
#pragma unroll
      for (int kc = 0; kc < 16; ++kc) {
        int coff = 8 * ((2 * kc + h) ^ col);       // undo chunk swizzle
        const s16x8 bh = *(const s16x8*)(KH + coff);
        const s16x8 bl = *(const s16x8*)(KL + coff);
        acc = __builtin_amdgcn_mfma_f32_32x32x16_bf16(qh[kc], bh, acc, 0, 0, 0);
        acc = __builtin_amdgcn_mfma_f32_32x32x16_bf16(ql[kc], bh, acc, 0, 0, 0);
        acc = __builtin_amdgcn_mfma_f32_32x32x16_bf16(qh[kc], bl, acc, 0, 0, 0);
      }
    }

    // ---- online softmax over n (32 cols = 32 lanes of this half) ----
    float al[16];
#pragma unroll
    for (int r = 0; r < 16; ++r) {
      float L = acc[r] * invd[r];
      float tm = L;
#pragma unroll
      for (int msk = 1; msk <= 16; msk <<= 1)
        tm = fmaxf(tm, __shfl_xor(tm, msk));
      float mnew = fmaxf(mrun[r], tm);
      al[r] = EXP2(mrun[r] - mnew);
      mrun[r] = mnew;
      u16 pq = bf16_rne(EXP2(L - mnew));
      float p = bf16_to_f(pq);                     // sum the QUANTIZED p
#pragma unroll
      for (int msk = 1; msk <= 16; msk <<= 1) p += __shfl_xor(p, msk);
      lrun[r] = al[r] * lrun[r] + p;
      sm.p[wave][((r & 3) + 8 * (r >> 2) + 4 * h) * PSTR + col] = pq;
    }
#pragma unroll
    for (int dt = 0; dt < 8; ++dt)
#pragma unroll
      for (int r = 0; r < 16; ++r) O[dt][r] *= al[r];

    // ---- PV: O += P @ V (P via per-wave LDS round-trip; vt swizzled) ----
#pragma unroll
    for (int kc2 = 0; kc2 < 2; ++kc2) {
      const s16x8 pa = *(const s16x8*)&sm.p[wave][col * PSTR + kc2 * 16 + 8 * h];
#pragma unroll
      for (int dt = 0; dt < 8; ++dt) {
        int d = dt * 32 + col;
        const s16x8 bv = *(const s16x8*)&sm.vt[cb][d * 32 + 8 * ((2 * kc2 + h) ^ (col & 3))];
        O[dt] = __builtin_amdgcn_mfma_f32_32x32x16_bf16(pa, bv, O[dt], 0, 0, 0);
      }
    }
    n0 += 32;
  }

  // ---- epilogue: partials (pO bf16, pm/pl fp32) ----
  {
    size_t obase = (size_t)split * B * DDIM;
#pragma unroll
    for (int r = 0; r < 16; ++r) {
      int gm = m0w + (r & 3) + 8 * (r >> 2) + 4 * h;
#pragma unroll
      for (int dt = 0; dt < 8; ++dt)
        pO[obase + (size_t)gm * DDIM + dt * 32 + col] = bf16_rne(O[dt][r]);
      if (col == 0) {
        pm[(size_t)split * B + gm] = mrun[r];
        pl[(size_t)split * B + gm] = lrun[r];
      }
    }
  }
}

// ---------------- combine ----------------
__global__ __launch_bounds__(256)
void combine_kernel(const void* __restrict__ t, const float* __restrict__ x,
                    const u16* __restrict__ pO, const float* __restrict__ pm,
                    const float* __restrict__ pl, float* __restrict__ out,
                    int nsplit, int B)
{
  int idx = blockIdx.x * 256 + threadIdx.x;   // over B*256
  int b = idx >> 8;
  const int tmode = classify_t_dtype(t);
  float M = -1e30f;
  for (int s = 0; s < nsplit; ++s) M = fmaxf(M, pm[(size_t)s * B + b]);
  float num = 0.f, den = 0.f;
  for (int s = 0; s < nsplit; ++s) {
    float w = EXP2(pm[(size_t)s * B + b] - M);
    num += w * bf16_to_f(pO[(size_t)s * B * DDIM + idx]);
    den += w * pl[(size_t)s * B + b];
  }
  float mean = num / den;
  float tv = load_t(t, b, tmode);
  float ts = EXP2(fmaf(tv, L2_10K, L2_001));
  float dd = ts * ts + SMIN2;
  out[idx] = ts * (mean - x[idx]) / dd;
}

extern "C" void kernel_launch(void* const* d_in, const int* in_sizes, int n_in,
                              void* d_out, int out_size, void* d_ws, size_t ws_size,
                              hipStream_t stream) {
  // Identify inputs BY SIZE: x has out_size elements, samples largest, t smallest.
  int xi = 0, si = 0, ti = 0;
  for (int i = 0; i < 3; ++i) {
    if (in_sizes[i] == out_size) xi = i;
    if (in_sizes[i] > in_sizes[si]) si = i;
    if (in_sizes[i] < in_sizes[ti]) ti = i;
  }
  const void*  t   = d_in[ti];                  // fp32 [B]
  const float* x   = (const float*)d_in[xi];    // fp32 [B,256]
  const float* smp = (const float*)d_in[si];    // fp32 [N,256]
  float* out = (float*)d_out;                   // fp32 [B,256]
  int B = out_size / DDIM;          // 4096
  int N = in_sizes[si] / DDIM;      // 8192

  // ws: gkhi | gklo | gvt | gxhi | gxlo | gs2 | pO(bf16) | pm | pl
  size_t splane = (size_t)N * DDIM;             // u16 elems
  size_t xplane = (size_t)B * DDIM;
  u16*   gkhi = (u16*)d_ws;
  u16*   gklo = gkhi + splane;
  u16*   gvt  = gklo + splane;
  u16*   gxhi = gvt  + splane;
  u16*   gxlo = gxhi + xplane;
  float* gs2  = (float*)(gxlo + xplane);
  u16*   pO   = (u16*)(gs2 + N);
  size_t fixed = splane * 6 + xplane * 4 + (size_t)N * 4;   // bytes
  size_t per   = xplane * 2 + (size_t)B * 8;                // pO bf16 + pm/pl
  int ns = 8;
  while (ns > 1 && fixed + (size_t)ns * per > ws_size) ns >>= 1;
  float* pm = (float*)(pO + (size_t)ns * xplane);
  float* pl = pm + (size_t)ns * B;

  prep_rows<<<dim3(N / 4), 256, 0, stream>>>(smp, gkhi, gklo, gs2, N);
  prep_x   <<<dim3(B / 4), 256, 0, stream>>>(x, gxhi, gxlo, B);
  prep_t   <<<dim3(N / 32), 256, 0, stream>>>(smp, gvt, N);
  flash_kernel<<<dim3(B / 128, ns), 256, 0, stream>>>(t, gkhi, gklo, gvt, gs2,
                                                      gxhi, gxlo, pO, pm, pl, B, N);
  combine_kernel<<<dim3(B * DDIM / 256), 256, 0, stream>>>(t, x, pO, pm, pl, out, ns, B);
}